// Round 12
// baseline (217.855 us; speedup 1.0000x reference)
//
#include <hip/hip_runtime.h>
#include <hip/hip_bf16.h>
#include <stdint.h>

typedef __attribute__((ext_vector_type(8))) short short8;
typedef __attribute__((ext_vector_type(4))) short short4v;
typedef __attribute__((ext_vector_type(4))) float f32x4;

#define B_ 2
#define S_ 2048
#define D_ 1024
#define H_ 16
#define DK_ 64
#define M_ (B_*S_)   // 4096

// workspace layout (in shorts):
//   [0 .. 12582912)          Q | K | VT, each M_*D_ bf16 (VT is [B,H,DK,S])
//   [12582912 .. 16777216)   Xb  bf16 (M_*D_)
//   [16777216 .. 19922944)   Wqb|Wkb|Wvb bf16 (D_*D_ each)
#define WS_QKV   0
#define WS_XB    12582912
#define WS_WB    16777216

// softmax-in-base-2: fold 1/sqrt(DK) * log2(e) into Q
#define QSCALE (0.125f * 1.44269504088896f)

// async global->LDS, 16B per lane; lds base wave-uniform, lane i -> base + i*16
#define GLL16(g, l) __builtin_amdgcn_global_load_lds( \
    (const __attribute__((address_space(1))) void*)(g), \
    (__attribute__((address_space(3))) void*)(l), 16, 0, 0)

#define WAIT_VM0 asm volatile("s_waitcnt vmcnt(0)" ::: "memory")
#define BARRIER_RAW asm volatile("s_barrier" ::: "memory")

static __device__ __forceinline__ short f2bf(float f){
  union { float f; unsigned u; } x; x.f = f;
  unsigned r = x.u + 0x7fff + ((x.u >> 16) & 1);   // round-to-nearest-even
  return (short)(r >> 16);
}

// ---------------------------------------------------------------------------
// Kernel 0: downcast f32 inputs (X, Wq, Wk, Wv) to bf16 in workspace.
// ---------------------------------------------------------------------------
__global__ __launch_bounds__(256) void cvt_bf16(
    const float* __restrict__ X,  const float* __restrict__ Wq,
    const float* __restrict__ Wk, const float* __restrict__ Wv,
    short* __restrict__ ws)
{
  const int z = blockIdx.z;
  const float* src; short* dst; int n;
  if (z == 0)      { src = X;  dst = ws + WS_XB;               n = M_*D_; }
  else if (z == 1) { src = Wq; dst = ws + WS_WB;               n = D_*D_; }
  else if (z == 2) { src = Wk; dst = ws + WS_WB + D_*D_;       n = D_*D_; }
  else             { src = Wv; dst = ws + WS_WB + 2*(D_*D_);   n = D_*D_; }
  const int stride = gridDim.x * blockDim.x * 4;
  for (int i = (blockIdx.x * blockDim.x + threadIdx.x) * 4; i < n; i += stride) {
    float4 v = *(const float4*)(src + i);
    short4v o;
    o.x = f2bf(v.x); o.y = f2bf(v.y); o.z = f2bf(v.z); o.w = f2bf(v.w);
    *(short4v*)(dst + i) = o;
  }
}

// ---------------------------------------------------------------------------
// Kernel 1: QKV projection, m97-structure. z in {0,1}: C = X@W^T + b ->
// [B,H,S,DK] (Q scaled by QSCALE). z==2: C^T = W@X^T + b -> VT [B,H,DK,S].
// 128x128 tile, BK=64, SINGLE-buffered [row][64-short] LDS (128B rows, slot
// s of row r holds chunk s^(r&7) -> measured-conflict-free b128 reads; the
// R5-R11 BK=32 64B-row layout had structural 4-way conflicts = 3.24M cyc).
// 16 K-iters: stage(8 GLL16/wave) -> vmcnt0+barrier -> 16 b128 + 32 MFMA ->
// barrier. Epilogue: acc -> padded LDS tile -> coalesced short8 stores.
// LDS 34816B -> 3 blocks/CU.
// ---------------------------------------------------------------------------
__global__ __launch_bounds__(256, 3) void qkv_gemm(
    const short* __restrict__ ws_in,
    const float* __restrict__ bq, const float* __restrict__ bk,
    const float* __restrict__ bv, short* __restrict__ qkv)
{
  const int z = blockIdx.z;
  const short* X  = ws_in + WS_XB;
  const short* Wm = ws_in + WS_WB + (size_t)z * (D_*D_);
  const float* bias = (z==0) ? bq : (z==1) ? bk : bv;
  short* out = qkv + (size_t)z * (M_*D_);

  __shared__ short lds[17408];   // A [128][64] @0, B @8192 (32KB); epilogue 34.8KB

  const int t = threadIdx.x;
  const int w = t >> 6, lane = t & 63;
  const int quad = lane >> 4, l16 = lane & 15;
  const int sw = l16 & 7;
  const int wm = w & 1, wn = w >> 1;
  const int m0 = blockIdx.y * 128, n0 = blockIdx.x * 128;

  // staging: GLL16 region = 8 rows x 128B; lane: row lr, slot lc; source
  // chunk csrc = lc ^ lr so slot s of row r holds chunk s^(r&7).
  const int lr = lane >> 3, lc = lane & 7;
  const int csrc = lc ^ lr;

  f32x4 acc[4][4];
  #pragma unroll
  for (int i=0;i<4;i++)
    #pragma unroll
    for (int j=0;j<4;j++) acc[i][j] = (f32x4){0.f,0.f,0.f,0.f};

  for (int k0 = 0; k0 < D_; k0 += 64) {
    #pragma unroll
    for (int p=0;p<4;p++){
      const int rb = (p*4 + w)*8;
      GLL16(X  + (size_t)(m0+rb+lr)*D_ + k0 + csrc*8, lds + rb*64);
      GLL16(Wm + (size_t)(n0+rb+lr)*D_ + k0 + csrc*8, lds + 8192 + rb*64);
    }
    WAIT_VM0;
    BARRIER_RAW;     // all waves' loads landed

    #pragma unroll
    for (int kc=0;kc<2;kc++){
      const int xch = (kc*4 + quad) ^ sw;
      short8 af[4], bfr[4];
      #pragma unroll
      for (int mt=0;mt<4;mt++)
        af[mt] = *(const short8*)(lds + (wm*64 + mt*16 + l16)*64 + xch*8);
      #pragma unroll
      for (int nt=0;nt<4;nt++)
        bfr[nt] = *(const short8*)(lds + 8192 + (wn*64 + nt*16 + l16)*64 + xch*8);
      if (z != 2) {
        #pragma unroll
        for (int mt=0;mt<4;mt++)
          #pragma unroll
          for (int nt=0;nt<4;nt++)
            acc[mt][nt] = __builtin_amdgcn_mfma_f32_16x16x32_bf16(af[mt], bfr[nt], acc[mt][nt], 0,0,0);
      } else {
        #pragma unroll
        for (int nt=0;nt<4;nt++)
          #pragma unroll
          for (int mt=0;mt<4;mt++)
            acc[nt][mt] = __builtin_amdgcn_mfma_f32_16x16x32_bf16(bfr[nt], af[mt], acc[nt][mt], 0,0,0);
      }
    }
    BARRIER_RAW;     // compute done before next iter's staging overwrites
  }

  __syncthreads();   // K-loop done; reuse LDS as epilogue tile [128][136]

  if (z != 2) {
    const float scale = (z==0) ? QSCALE : 1.0f;
    #pragma unroll
    for (int nt=0;nt<4;nt++){
      const int col_l = wn*64 + nt*16 + l16;
      const float bvv = bias[n0 + col_l];
      #pragma unroll
      for (int mt=0;mt<4;mt++)
        #pragma unroll
        for (int i=0;i<4;i++){
          const int row_l = wm*64 + mt*16 + quad*4 + i;
          lds[row_l*136 + col_l] = f2bf((acc[mt][nt][i] + bvv) * scale);
        }
    }
    __syncthreads();
    #pragma unroll
    for (int k=0;k<8;k++){
      const int cid = k*256 + t;
      const int row = cid >> 4, cc = cid & 15;
      short8 vv = *(const short8*)(lds + row*136 + cc*8);
      const int m = m0 + row, bidx = m >> 11, s = m & 2047;
      const int n = n0 + cc*8, h = n >> 6, dd = n & 63;
      *(short8*)(out + (((size_t)(bidx*H_ + h))*S_ + s)*DK_ + dd) = vv;
    }
  } else {
    #pragma unroll
    for (int nt=0;nt<4;nt++)
      #pragma unroll
      for (int i=0;i<4;i++){
        const int n_l = wn*64 + nt*16 + quad*4 + i;
        const float bvv = bias[n0 + n_l];
        #pragma unroll
        for (int mt=0;mt<4;mt++){
          const int m_l = wm*64 + mt*16 + l16;
          lds[n_l*136 + m_l] = f2bf(acc[nt][mt][i] + bvv);
        }
      }
    __syncthreads();
    #pragma unroll
    for (int k=0;k<8;k++){
      const int cid = k*256 + t;
      const int rowN = cid >> 4, cc = cid & 15;
      short8 vv = *(const short8*)(lds + rowN*136 + cc*8);
      const int n = n0 + rowN, h = n >> 6, dd = n & 63;
      const int m = m0 + cc*8, bidx = m >> 11, s0 = m & 2047;
      *(short8*)(out + (((size_t)(bidx*H_ + h))*DK_ + dd)*S_ + s0) = vv;
    }
  }
}

// ---------------------------------------------------------------------------
// Kernel 2: flash-style causal attention per (bh, 128-query tile).
// (Unchanged from R11: Q in registers, K/V^T double-buffered, 48KB LDS ->
// 3 blocks/CU, S^T orientation, v_perm truncating P pack, base-2 softmax.)
// ---------------------------------------------------------------------------
__global__ __launch_bounds__(256, 3) void attn(
    const short* __restrict__ qkv, float* __restrict__ out)
{
  const int bh = blockIdx.y;                    // b*16 + h, 0..31
  const int qt = (gridDim.x - 1) - blockIdx.x;  // longest blocks first
  const short* Q  = qkv + (size_t)bh * (S_*DK_);
  const short* K  = Q + (size_t)(M_*D_);
  const short* VT = qkv + (size_t)(2*M_*D_) + (size_t)bh * (DK_*S_);  // [d][s]

  __shared__ short Kbuf[2][4096];   // [64][64] swizzled,  16KB
  __shared__ short Vbuf[2][4096];   // [64(d)][64(key)],   16KB
  __shared__ short Ps[8192];        // [qrow 128][64 keys] swizzled, 16KB

  const int t = threadIdx.x;
  const int w = t >> 6, lane = t & 63;
  const int quad = lane >> 4, l16 = lane & 15;
  const int sw = l16 & 7;
  const int lr = lane >> 3, lc = lane & 7;
  const int csrc = lc ^ lr;

  // Q fragments (B-operand) straight to registers
  short8 bq[2][2];
  #pragma unroll
  for (int kc=0;kc<2;kc++)
    #pragma unroll
    for (int mt=0;mt<2;mt++)
      bq[kc][mt] = *(const short8*)(Q + (size_t)(qt*128 + w*32 + mt*16 + l16)*DK_
                                      + (kc*4 + quad)*8);

  const int nkt = 2*qt + 2;
  // prime: K/V tile 0 into buffer 0
  #pragma unroll
  for (int j=0;j<2;j++){
    const int rb = (j*4 + w)*8;
    GLL16(K  + (size_t)(rb + lr)*DK_ + csrc*8, &Kbuf[0][0] + rb*64);
    GLL16(VT + (size_t)(rb + lr)*S_  + csrc*8, &Vbuf[0][0] + rb*64);
  }

  f32x4 o[2][4];
  float lsum[2];
  #pragma unroll
  for (int mt=0;mt<2;mt++){
    #pragma unroll
    for (int nd=0;nd<4;nd++) o[mt][nd] = (f32x4){0.f,0.f,0.f,0.f};
    lsum[mt] = 0.f;
  }

  const int pw_half = (quad & 1) * 4;
  const int pw_ckb  = quad >> 1;
  int cur = 0;

  for (int kt = 0; kt < nkt; kt++){
    WAIT_VM0;        // buf[cur] (and Q reg loads at kt==0) complete
    BARRIER_RAW;
    const int nxt = cur ^ 1;
    if (kt + 1 < nkt) {
      const int kb2 = (kt+1)*64;
      short* Kn = &Kbuf[nxt][0];
      short* Vn = &Vbuf[nxt][0];
      #pragma unroll
      for (int j=0;j<2;j++){
        const int rb = (j*4 + w)*8;
        GLL16(K  + (size_t)(kb2 + rb + lr)*DK_ + csrc*8, Kn + rb*64);
        GLL16(VT + (size_t)(rb + lr)*S_ + kb2 + csrc*8,  Vn + rb*64);
      }
    }
    const short* Kc = &Kbuf[cur][0];
    const short* Vc = &Vbuf[cur][0];
    const int kb = kt*64;

    // S^T = K @ Q^T: C row = key = ntk*16+quad*4+i, col = qrow = w*32+mt*16+l16
    f32x4 sc[4][2];
    #pragma unroll
    for (int ntk=0;ntk<4;ntk++)
      #pragma unroll
      for (int mt=0;mt<2;mt++) sc[ntk][mt] = (f32x4){0.f,0.f,0.f,0.f};
    #pragma unroll
    for (int kc=0;kc<2;kc++){
      const int xch = (kc*4 + quad) ^ sw;
      short8 ak[4];
      #pragma unroll
      for (int ntk=0;ntk<4;ntk++)
        ak[ntk] = *(const short8*)(Kc + (ntk*16 + l16)*64 + xch*8);
      #pragma unroll
      for (int ntk=0;ntk<4;ntk++)
        #pragma unroll
        for (int mt=0;mt<2;mt++)
          sc[ntk][mt] = __builtin_amdgcn_mfma_f32_16x16x32_bf16(ak[ntk], bq[kc][mt], sc[ntk][mt], 0,0,0);
    }

    // causal mask
    const int q0w = qt*128 + w*32;
    if (kb + 63 > q0w) {
      #pragma unroll
      for (int ntk=0;ntk<4;ntk++)
        #pragma unroll
        for (int mt=0;mt<2;mt++){
          const int qg = q0w + mt*16 + l16;
          #pragma unroll
          for (int i=0;i<4;i++){
            const int kg = kb + ntk*16 + quad*4 + i;
            if (kg > qg) sc[ntk][mt][i] = -3.0e38f;
          }
        }
    }

    // p = exp2(score); v_perm pair-pack (truncating bf16) -> one b64 store
    #pragma unroll
    for (int mt=0;mt<2;mt++){
      const int r = w*32 + mt*16 + l16;
      #pragma unroll
      for (int ntk=0;ntk<4;ntk++){
        float p0 = __builtin_amdgcn_exp2f(sc[ntk][mt][0]);
        float p1 = __builtin_amdgcn_exp2f(sc[ntk][mt][1]);
        float p2 = __builtin_amdgcn_exp2f(sc[ntk][mt][2]);
        float p3 = __builtin_amdgcn_exp2f(sc[ntk][mt][3]);
        lsum[mt] += (p0+p1) + (p2+p3);
        unsigned lo = __builtin_amdgcn_perm(__float_as_uint(p1), __float_as_uint(p0), 0x07060302u);
        unsigned hi = __builtin_amdgcn_perm(__float_as_uint(p3), __float_as_uint(p2), 0x07060302u);
        const int slot = (ntk*2 + pw_ckb) ^ sw;
        *(uint2*)(Ps + r*64 + slot*8 + pw_half) = make_uint2(lo, hi);
      }
    }
    asm volatile("" ::: "memory");  // same-wave LDS RAW: keep reads below writes

    // PV: o += P @ V
    #pragma unroll
    for (int kc=0;kc<2;kc++){
      const int xch = (kc*4 + quad) ^ sw;
      short8 pa[2], vb[4];
      #pragma unroll
      for (int mt=0;mt<2;mt++)
        pa[mt] = *(const short8*)(Ps + (w*32 + mt*16 + l16)*64 + xch*8);
      #pragma unroll
      for (int nd=0;nd<4;nd++)
        vb[nd] = *(const short8*)(Vc + (nd*16 + l16)*64 + xch*8);
      #pragma unroll
      for (int mt=0;mt<2;mt++)
        #pragma unroll
        for (int nd=0;nd<4;nd++)
          o[mt][nd] = __builtin_amdgcn_mfma_f32_16x16x32_bf16(pa[mt], vb[nd], o[mt][nd], 0,0,0);
    }
    cur = nxt;
  }

  // epilogue: reduce row sums over quads, redistribute, scale, store f32
  const int bb = bh >> 4, h = bh & 15;
  float linv[2];
  #pragma unroll
  for (int mt=0;mt<2;mt++){
    float rs = lsum[mt];
    rs += __shfl_xor(rs, 16, 64);
    rs += __shfl_xor(rs, 32, 64);
    linv[mt] = 1.0f / rs;
  }
  #pragma unroll
  for (int mt=0;mt<2;mt++){
    #pragma unroll
    for (int i=0;i<4;i++){
      const float lw = __shfl(linv[mt], (quad<<4) + (quad<<2) + i, 64);
      const int q = qt*128 + w*32 + mt*16 + quad*4 + i;
      #pragma unroll
      for (int nd=0;nd<4;nd++){
        const int d = nd*16 + l16;
        out[ ((size_t)bb*S_ + q)*D_ + h*DK_ + d ] = o[mt][nd][i] * lw;
      }
    }
  }
}

extern "C" void kernel_launch(void* const* d_in, const int* in_sizes, int n_in,
                              void* d_out, int out_size, void* d_ws, size_t ws_size,
                              hipStream_t stream)
{
  (void)in_sizes; (void)n_in; (void)out_size; (void)ws_size;
  const float* X  = (const float*)d_in[0];
  const float* Wq = (const float*)d_in[1];
  const float* bq = (const float*)d_in[2];
  const float* Wk = (const float*)d_in[3];
  const float* bk = (const float*)d_in[4];
  const float* Wv = (const float*)d_in[5];
  const float* bv = (const float*)d_in[6];
  short* ws  = (short*)d_ws;
  float* out = (float*)d_out;

  dim3 g0(1024, 1, 4);
  cvt_bf16<<<g0, dim3(256,1,1), 0, stream>>>(X, Wq, Wk, Wv, ws);
  dim3 g1(D_/128, M_/128, 3);       // 8 x 32 x 3
  qkv_gemm<<<g1, dim3(256,1,1), 0, stream>>>(ws, bq, bk, bv, ws + WS_QKV);
  dim3 g2(S_/128, B_*H_);           // 16 x 32
  attn<<<g2, dim3(256,1,1), 0, stream>>>(ws + WS_QKV, out);
}